// Round 2
// baseline (168.706 us; speedup 1.0000x reference)
//
#include <hip/hip_runtime.h>

#define B_   256
#define E_   64
#define G_   2000
#define P_   512
#define K2   2048      // G padded up to a multiple of BK
#define BN   32
#define BK   64
#define NS   (K2/BK)   // 32 K-steps

typedef __bf16 bf16x8 __attribute__((ext_vector_type(8)));
typedef float floatx4 __attribute__((ext_vector_type(4)));

__global__ __launch_bounds__(256)
void cvt_x_kernel(const float* __restrict__ x, __bf16* __restrict__ xb) {
    int col = blockIdx.x * 256 + threadIdx.x;
    int row = blockIdx.y;
    if (col < K2) {
        float v = (col < G_) ? x[(size_t)row * G_ + col] : 0.f;
        xb[(size_t)row * K2 + col] = (__bf16)v;
    }
}

// LDS tile: [buf][n(=p local, 32)][k local, 64] bf16, 128 B rows, XOR-swizzled:
// bf16 index = n*64 + (kcol ^ ((n&7)<<3))   (kcol multiple of 8 -> 16B aligned)
template<bool USE_WS>
__global__ __launch_bounds__(256, 4)
void masked_gemm_kernel(const float* __restrict__ x,
                        const __bf16* __restrict__ xb,
                        const float* __restrict__ weight,
                        const float* __restrict__ bias,
                        const float* __restrict__ mask,
                        float* __restrict__ out)
{
    __shared__ __bf16 wlds[2][BN * BK];

    const int tid = threadIdx.x;
    const int bid = blockIdx.x;          // 1024 blocks
    // XCD-aware: xcd = bid&7 owns p-slab [xcd*64, xcd*64+64) -> mask/x L2-hot
    const int xcd = bid & 7;
    const int q   = bid >> 3;            // 0..127
    const int nt  = xcd * 2 + (q & 1);   // 0..15
    const int e   = q >> 1;              // 0..63
    const int p0  = nt * BN;

    const int lane = tid & 63;
    const int wv   = tid >> 6;           // wave 0..3 -> rows wv*64..wv*64+63
    const int ln   = lane & 15;
    const int hi   = lane >> 4;          // k-slot group 0..3

    // staging coords: thread loads 8 consecutive g at octet sg, column sp
    const int sp = tid & 31;             // p-local 0..31
    const int sg = tid >> 5;             // g-octet 0..7

    const float* wbase = weight + (size_t)e * G_ * P_ + p0 + sp;
    const float* mbase = mask + p0 + sp;

    // swizzled LDS write index (bf16 units)
    const int wr_idx = sp * BK + ((sg * 8) ^ ((sp & 7) << 3));

    floatx4 acc[4][2];
    #pragma unroll
    for (int i = 0; i < 4; ++i)
        #pragma unroll
        for (int j = 0; j < 2; ++j)
            acc[i][j] = (floatx4)0.f;

    float wr[8], mr[8];

    // prologue: stage K-step 0 into buffer 0 (g 0..63 all valid)
    {
        #pragma unroll
        for (int j = 0; j < 8; ++j) {
            wr[j] = wbase[(size_t)(sg * 8 + j) * P_];
            mr[j] = mbase[(size_t)(sg * 8 + j) * P_];
        }
        bf16x8 h;
        #pragma unroll
        for (int j = 0; j < 8; ++j) h[j] = (__bf16)(wr[j] * mr[j]);
        *(bf16x8*)&wlds[0][wr_idx] = h;
    }

    const int mrow0 = wv * 64;

    for (int s = 0; s < NS; ++s) {
        const int cur = s & 1;
        const int kb = s * BK;
        const bool more = (s + 1 < NS);

        __syncthreads();                       // buffer `cur` ready

        // issue global loads for next K-step (overlap with MFMA below)
        bool sval = false;
        if (more) {
            const int g0 = kb + BK + sg * 8;   // octet fully valid or fully pad
            sval = (g0 < G_);
            if (sval) {
                #pragma unroll
                for (int j = 0; j < 8; ++j) {
                    wr[j] = wbase[(size_t)(g0 + j) * P_];
                    mr[j] = mbase[(size_t)(g0 + j) * P_];
                }
            }
        }

        // compute on buffer cur: 2 x (2 ds_read_b128 + 4 a-loads + 8 MFMA)
        #pragma unroll
        for (int kk = 0; kk < 2; ++kk) {
            bf16x8 bfrag[2];
            #pragma unroll
            for (int ni = 0; ni < 2; ++ni) {
                const int n = ni * 16 + ln;
                const int kcol = kk * 32 + hi * 8;
                bfrag[ni] = *(const bf16x8*)&wlds[cur][n * BK + (kcol ^ ((n & 7) << 3))];
            }
            bf16x8 afrag[4];
            if (USE_WS) {
                #pragma unroll
                for (int mi = 0; mi < 4; ++mi) {
                    const int row = mrow0 + mi * 16 + ln;
                    afrag[mi] = *(const bf16x8*)&xb[(size_t)row * K2 + kb + kk * 32 + hi * 8];
                }
            } else {
                #pragma unroll
                for (int mi = 0; mi < 4; ++mi) {
                    const int row = mrow0 + mi * 16 + ln;
                    const int k = kb + kk * 32 + hi * 8;
                    bf16x8 a;
                    #pragma unroll
                    for (int j = 0; j < 8; ++j)
                        a[j] = (k + j < G_) ? (__bf16)x[(size_t)row * G_ + k + j] : (__bf16)0.f;
                    afrag[mi] = a;
                }
            }
            #pragma unroll
            for (int mi = 0; mi < 4; ++mi)
                #pragma unroll
                for (int ni = 0; ni < 2; ++ni)
                    acc[mi][ni] = __builtin_amdgcn_mfma_f32_16x16x32_bf16(
                                      afrag[mi], bfrag[ni], acc[mi][ni], 0, 0, 0);
        }

        // convert + swizzled write of next tile (waits the global loads here)
        if (more) {
            bf16x8 h;
            if (sval) {
                #pragma unroll
                for (int j = 0; j < 8; ++j) h[j] = (__bf16)(wr[j] * mr[j]);
            } else {
                #pragma unroll
                for (int j = 0; j < 8; ++j) h[j] = (__bf16)0.f;
            }
            *(bf16x8*)&wlds[cur ^ 1][wr_idx] = h;
        }
    }

    // epilogue: D[row=(lane>>4)*4+j][col=lane&15], add bias, nontemporal stores
    #pragma unroll
    for (int ni = 0; ni < 2; ++ni) {
        const int p = p0 + ni * 16 + ln;
        const float bv = bias[e * P_ + p];
        #pragma unroll
        for (int mi = 0; mi < 4; ++mi) {
            #pragma unroll
            for (int j = 0; j < 4; ++j) {
                const int b = mrow0 + mi * 16 + hi * 4 + j;
                __builtin_nontemporal_store(acc[mi][ni][j] + bv,
                    &out[(size_t)b * (E_ * P_) + (size_t)e * P_ + p]);
            }
        }
    }
}

extern "C" void kernel_launch(void* const* d_in, const int* in_sizes, int n_in,
                              void* d_out, int out_size, void* d_ws, size_t ws_size,
                              hipStream_t stream) {
    const float* x      = (const float*)d_in[0];
    const float* weight = (const float*)d_in[1];
    const float* bias   = (const float*)d_in[2];
    const float* mask   = (const float*)d_in[3];
    float* out = (float*)d_out;

    const size_t xb_bytes = (size_t)B_ * K2 * sizeof(__bf16);
    if (ws_size >= xb_bytes) {
        __bf16* xb = (__bf16*)d_ws;
        dim3 g1((K2 + 255) / 256, B_);
        cvt_x_kernel<<<g1, dim3(256), 0, stream>>>(x, xb);
        masked_gemm_kernel<true><<<dim3(1024), dim3(256), 0, stream>>>(x, xb, weight, bias, mask, out);
    } else {
        masked_gemm_kernel<false><<<dim3(1024), dim3(256), 0, stream>>>(x, nullptr, weight, bias, mask, out);
    }
}

// Round 3
// 83.963 us; speedup vs baseline: 2.0093x; 2.0093x over previous
//
#include <hip/hip_runtime.h>

#define B_   256
#define E_   64
#define G_   2000
#define P_   512
#define K2   2048      // G padded to multiple of BK (xb zero-filled)
#define BK   64
#define NS   (K2/BK)   // 32 K-steps
#define PT   64        // p columns per block (16 per wave)

typedef __bf16 bf16x8 __attribute__((ext_vector_type(8)));
typedef float floatx4 __attribute__((ext_vector_type(4)));
typedef unsigned int u32;

__global__ __launch_bounds__(256)
void cvt_x_kernel(const float* __restrict__ x, __bf16* __restrict__ xb) {
    int col = blockIdx.x * 256 + threadIdx.x;   // 0..2047
    int row = blockIdx.y;
    float v = (col < G_) ? x[(size_t)row * G_ + col] : 0.f;
    xb[(size_t)row * K2 + col] = (__bf16)v;
}

// async global->LDS, 16B per lane, linear LDS dest (uniform base + lane*16)
__device__ __forceinline__ void gll16(const void* g, void* l) {
    __builtin_amdgcn_global_load_lds(
        (const __attribute__((address_space(1))) u32*)(uintptr_t)g,
        (__attribute__((address_space(3))) u32*)(uintptr_t)l,
        16, 0, 0);
}

// A (=x, m=b rows) staged in LDS: [buf][row][64k] bf16, 128B rows.
// 128B pitch is bank-aligned -> XOR-swizzle 16B chunks: LDS chunk cc of row r
// holds x k-chunk (cc ^ (r&7)). Linear gll dest + pre-swizzled global source,
// swizzled ds_read (rule #21). B (=weight*mask, n=p cols) gathered straight
// into registers: lane ln = p, 8 strided dwords per k-octet = the B-fragment.
template<bool USE_WS>
__global__ __launch_bounds__(256, 2)
void masked_gemm_kernel(const float* __restrict__ x,
                        const __bf16* __restrict__ xb,
                        const float* __restrict__ weight,
                        const float* __restrict__ bias,
                        const float* __restrict__ mask,
                        float* __restrict__ out)
{
    __shared__ __attribute__((aligned(128))) __bf16 alds[2][B_ * BK];  // 2 x 32KB

    const int tid  = threadIdx.x;
    const int lane = tid & 63;
    const int wv   = tid >> 6;           // wave 0..3, owns p slice wv*16
    const int ln   = lane & 15;
    const int hi   = lane >> 4;          // k-octet group

    const int bid = blockIdx.x;          // 512 blocks
    const int pt  = bid & 7;             // p-tile -> XCD (bid%8 round-robin)
    const int e   = bid >> 3;            // expert 0..63
    const int pw  = pt * PT + wv * 16;   // this wave's p base

    const float* wcol = weight + (size_t)e * G_ * P_ + pw + ln;
    const float* mcol = mask   + (size_t)(pw + ln);

    // staging lane coords: row group of 8, 16B chunk within 128B row
    const int srow = lane >> 3;          // 0..7
    const int schk = lane & 7;           // 0..7

    floatx4 acc[16];
    #pragma unroll
    for (int i = 0; i < 16; ++i) acc[i] = (floatx4)0.f;

    float wr[16], mr[16];
    bf16x8 bcur[2], bnext[2];

    // ---- prologue: stage A tile 0, load+cvt B block 0 ----
    #pragma unroll
    for (int i = 0; i < 8; ++i) {
        const int r0  = wv * 64 + i * 8;
        const int row = r0 + srow;
        if (USE_WS) {
            const __bf16* src = xb + (size_t)row * K2 + ((schk ^ (row & 7)) << 3);
            gll16(src, (void*)&alds[0][r0 * BK]);
        } else {
            const int k0 = (schk ^ (row & 7)) << 3;
            bf16x8 v;
            #pragma unroll
            for (int j = 0; j < 8; ++j)
                v[j] = (k0 + j < G_) ? (__bf16)x[(size_t)row * G_ + k0 + j] : (__bf16)0.f;
            *(bf16x8*)&alds[0][row * BK + schk * 8] = v;
        }
    }
    #pragma unroll
    for (int kk = 0; kk < 2; ++kk)
        #pragma unroll
        for (int j = 0; j < 8; ++j) {
            const int g = kk * 32 + hi * 8 + j;       // all < 2000
            wr[kk * 8 + j] = wcol[(size_t)g * P_];
            mr[kk * 8 + j] = mcol[(size_t)g * P_];
        }
    #pragma unroll
    for (int kk = 0; kk < 2; ++kk)
        #pragma unroll
        for (int j = 0; j < 8; ++j)
            bcur[kk][j] = (__bf16)(wr[kk * 8 + j] * mr[kk * 8 + j]);
    __syncthreads();

    // ---- main loop: compute(t) reads only LDS+regs; prefetch(t+1) in flight ----
    for (int s = 0; s < NS; ++s) {
        const int buf = s & 1;
        const bool more = (s + 1) < NS;
        const int kb1 = (s + 1) * BK;

        if (more) {
            // stage A tile t+1 into alds[buf^1] (async, drains at barrier)
            #pragma unroll
            for (int i = 0; i < 8; ++i) {
                const int r0  = wv * 64 + i * 8;
                const int row = r0 + srow;
                if (USE_WS) {
                    const __bf16* src = xb + (size_t)row * K2 + kb1 + ((schk ^ (row & 7)) << 3);
                    gll16(src, (void*)&alds[buf ^ 1][r0 * BK]);
                } else {
                    const int k0 = kb1 + ((schk ^ (row & 7)) << 3);
                    bf16x8 v;
                    #pragma unroll
                    for (int j = 0; j < 8; ++j)
                        v[j] = (k0 + j < G_) ? (__bf16)x[(size_t)row * G_ + k0 + j] : (__bf16)0.f;
                    *(bf16x8*)&alds[buf ^ 1][row * BK + schk * 8] = v;
                }
            }
            // weight/mask gather t+1 (uniform-branch tail guard, last step only)
            if (kb1 + BK <= G_) {
                #pragma unroll
                for (int kk = 0; kk < 2; ++kk)
                    #pragma unroll
                    for (int j = 0; j < 8; ++j) {
                        const int g = kb1 + kk * 32 + hi * 8 + j;
                        wr[kk * 8 + j] = wcol[(size_t)g * P_];
                        mr[kk * 8 + j] = mcol[(size_t)g * P_];
                    }
            } else {
                #pragma unroll
                for (int kk = 0; kk < 2; ++kk)
                    #pragma unroll
                    for (int j = 0; j < 8; ++j) {
                        const int g = kb1 + kk * 32 + hi * 8 + j;
                        const bool ok = g < G_;
                        wr[kk * 8 + j] = ok ? wcol[(size_t)g * P_] : 0.f;
                        mr[kk * 8 + j] = ok ? mcol[(size_t)g * P_] : 0.f;
                    }
            }
        }

        // compute: 32 ds_read_b128 + 32 MFMA, no vmem dependence
        #pragma unroll
        for (int kk = 0; kk < 2; ++kk) {
            #pragma unroll
            for (int mi = 0; mi < 16; ++mi) {
                const int row = mi * 16 + ln;
                const int cc  = (kk * 4 + hi) ^ (row & 7);
                bf16x8 a = *(const bf16x8*)&alds[buf][row * BK + cc * 8];
                acc[mi] = __builtin_amdgcn_mfma_f32_16x16x32_bf16(a, bcur[kk], acc[mi], 0, 0, 0);
            }
        }

        // finish prefetch: cvt (waits w/m); barrier drains gll (vmcnt 0)
        if (more) {
            #pragma unroll
            for (int kk = 0; kk < 2; ++kk)
                #pragma unroll
                for (int j = 0; j < 8; ++j)
                    bnext[kk][j] = (__bf16)(wr[kk * 8 + j] * mr[kk * 8 + j]);
        }
        __syncthreads();
        if (more) {
            bcur[0] = bnext[0];
            bcur[1] = bnext[1];
        }
    }

    // ---- epilogue: D row m=b=(hi*4+j within mi tile), col n=p=ln ----
    const float bv = bias[e * P_ + pw + ln];
    #pragma unroll
    for (int mi = 0; mi < 16; ++mi) {
        #pragma unroll
        for (int j = 0; j < 4; ++j) {
            const int b = mi * 16 + hi * 4 + j;
            __builtin_nontemporal_store(acc[mi][j] + bv,
                &out[(size_t)b * (E_ * P_) + (size_t)e * P_ + pw + ln]);
        }
    }
}

extern "C" void kernel_launch(void* const* d_in, const int* in_sizes, int n_in,
                              void* d_out, int out_size, void* d_ws, size_t ws_size,
                              hipStream_t stream) {
    const float* x      = (const float*)d_in[0];
    const float* weight = (const float*)d_in[1];
    const float* bias   = (const float*)d_in[2];
    const float* mask   = (const float*)d_in[3];
    float* out = (float*)d_out;

    const size_t xb_bytes = (size_t)B_ * K2 * sizeof(__bf16);
    if (ws_size >= xb_bytes) {
        __bf16* xb = (__bf16*)d_ws;
        dim3 g1(K2 / 256, B_);
        cvt_x_kernel<<<g1, dim3(256), 0, stream>>>(x, xb);
        masked_gemm_kernel<true><<<dim3(512), dim3(256), 0, stream>>>(x, xb, weight, bias, mask, out);
    } else {
        masked_gemm_kernel<false><<<dim3(512), dim3(256), 0, stream>>>(x, nullptr, weight, bias, mask, out);
    }
}